// Round 9
// baseline (253.474 us; speedup 1.0000x reference)
//
#include <hip/hip_runtime.h>

// VQ nearest-embedding, fused split-fp16 MFMA.
// argmin_k ||x-e_k||^2 == argmin_k (0.5*||e_k||^2 - x.e_k).
// x = xh+xl, e = eh+el (fp16 RNE splits); 3 MFMA terms (hh, hl, lh).
// R12 (143us): A+B LDS dbuf, distance-2 prefetch. 6.3M bank conflicts
//      (= A b32 staging writes, 8-way at 80B row stride; model confirmed
//      by R13's conflicts=0).
// R13 (163us): A in-register, split in-loop -> conflicts 0 but split16
//      VALU duplicated x4 across n-groups (VALUBusy 46%). Net loss.
// R14: A split ONCE in pack_x (R6's proven out-as-scratch slab layout;
//      absmax-0-validated aliasing: each block reads only its own columns
//      of its slab; gather writes are column-disjoint across blocks).
//      Hot loop A = 16 raw uint loads/wave/chunk (the packed uint IS
//      pk(h[2j],h[2j+1]) = R13's fragment word -> bit-identical).
//      Zero A VALU, zero A LDS, conflicts stay 0. B path = R13 unchanged
//      (LDS dbuf, distance-2, LDA=40, measured conflict-free).

typedef __attribute__((ext_vector_type(8))) _Float16 half8v;  // 8 fp16 = 4 VGPRs
typedef __attribute__((ext_vector_type(16))) float floatx16;  // 32x32 acc
typedef unsigned int uint;
typedef unsigned short ushort;

#define DD 256
#define KK 2048
#define SS 1024
#define NN 32768
#define MT 128      // latents per block
#define NTT 256     // codes per kt tile (8 tiles cover K=2048)
#define CD 32       // chunk K-depth (halfs)
#define LDA 40      // B LDS row stride in fp16 elems (80 B)
#define MFMA_F16 __builtin_amdgcn_mfma_f32_32x32x16_f16

#define XSLAB  262144   // uints per batch slab of packed x: 2 planes * 128 d2 * 1024 s
#define XPLANE 131072   // uints per plane within a slab
#define EPLANE 262144   // (doc) uints per packed-emb plane equivalent

union HU { _Float16 f; ushort u; };
union FragU { uint u[4]; half8v v; };

__device__ __forceinline__ void split16(float v, ushort& h, ushort& l) {
    HU a, b;
    a.f = (_Float16)v;                       // RNE
    b.f = (_Float16)(v - (float)a.f);
    h = a.u; l = b.u;
}

__device__ __forceinline__ uint pk(ushort a, ushort b) {
    return (uint)a | ((uint)b << 16);
}

// 64 blocks: block b covers codes [b*32, b*32+32); 8 threads/code sum 32 d's.
__global__ __launch_bounds__(256) void hn_kernel(const float* __restrict__ emb,
                                                 float* __restrict__ hn) {
    __shared__ float red[256];
    const int tid = threadIdx.x;
    const int k = blockIdx.x * 32 + (tid & 31);
    const int j = tid >> 5;              // 0..7: d-chunk
    float a = 0.f;
#pragma unroll
    for (int i = 0; i < 32; ++i) {
        float e = emb[(size_t)(j * 32 + i) * KK + k];
        a += e * e;
    }
    red[tid] = a;
    __syncthreads();
    if (j == 0) {
        float s = a;
#pragma unroll
        for (int g = 1; g < 8; ++g) s += red[g * 32 + (tid & 31)];
        hn[k] = 0.5f * s;
    }
}

// emb (d,k) f32 -> epk quad-interleaved uint4 planes:
//   uint4 index (q*2 + p)*KK + k holds, for plane p in {h,l}, code k,
//   packed d-pairs of quad q (element j = pack(d=8q+2j, d=8q+2j+1)).
__global__ __launch_bounds__(256) void pack_emb(const float* __restrict__ emb,
                                                uint4* __restrict__ epk) {
    int idx = blockIdx.x * 256 + threadIdx.x;     // 65536 = 32 quads * 2048 k
    int k = idx & (KK - 1);
    int q = idx >> 11;                            // d-quad: d = 8q..8q+7
    ushort h[8], l[8];
#pragma unroll
    for (int j = 0; j < 8; ++j) {
        float e = emb[(size_t)(8 * q + j) * KK + k];
        split16(e, h[j], l[j]);
    }
    uint4 H, L;
    H.x = pk(h[0], h[1]); H.y = pk(h[2], h[3]);
    H.z = pk(h[4], h[5]); H.w = pk(h[6], h[7]);
    L.x = pk(l[0], l[1]); L.y = pk(l[2], l[3]);
    L.z = pk(l[4], l[5]); L.w = pk(l[6], l[7]);
    epk[(size_t)(q * 2 + 0) * KK + k] = H;
    epk[(size_t)(q * 2 + 1) * KK + k] = L;
}

// x (bq,d,s) f32 -> out-as-scratch slabs: [bq][plane][d2][s] packed uints.
// uint at (d2, s) = pk(split(x[2*d2][s]), split(x[2*d2+1][s])).
__global__ __launch_bounds__(256) void pack_x(const float* __restrict__ x,
                                              uint* __restrict__ px) {
    int idx = blockIdx.x * 256 + threadIdx.x;     // 1048576 = 32 bq * 128 d2 * 256 s4
    int s4 = idx & 255;
    int d2 = (idx >> 8) & 127;
    int bq = idx >> 15;
    const float4* xp = reinterpret_cast<const float4*>(
        x + ((size_t)(bq * DD + 2 * d2)) * SS) + s4;
    float4 a = xp[0];
    float4 b = xp[SS / 4];                        // next d row
    ushort h0, l0, h1, l1;
    uint4 th, tl;
    split16(a.x, h0, l0); split16(b.x, h1, l1);
    th.x = pk(h0, h1); tl.x = pk(l0, l1);
    split16(a.y, h0, l0); split16(b.y, h1, l1);
    th.y = pk(h0, h1); tl.y = pk(l0, l1);
    split16(a.z, h0, l0); split16(b.z, h1, l1);
    th.z = pk(h0, h1); tl.z = pk(l0, l1);
    split16(a.w, h0, l0); split16(b.w, h1, l1);
    th.w = pk(h0, h1); tl.w = pk(l0, l1);
    size_t o4 = (size_t)bq * (XSLAB / 4) + (size_t)d2 * (SS / 4) + s4;
    reinterpret_cast<uint4*>(px)[o4] = th;
    reinterpret_cast<uint4*>(px)[o4 + XPLANE / 4] = tl;
}

// PRE: A from packed out-scratch, B from quad-packed epk.
// !PRE: A from x f32 (in-loop split), B from emb f32 (in-loop split).
template <bool PRE>
__global__ __launch_bounds__(1024, 4) void vq_fused(
        const float* __restrict__ x, const float* __restrict__ emb,
        const float* __restrict__ hn, const uint4* __restrict__ epk,
        float* out) {
    __shared__ ushort Bh[2][NTT * LDA], Bl[2][NTT * LDA];   // 20 KB each plane/buf
    __shared__ float sv[4][MT];
    __shared__ int   sc[4][MT];
    __shared__ int   bc[MT];

    const int tid = threadIdx.x;
    const int lane = tid & 63;
    const int wid = tid >> 6;          // 16 waves: 4(m) x 4(n)
    const int colk = lane & 31;
    const int half = lane >> 5;
    const int wm = (wid & 3) * 32;     // 4 m-tiles of 32 cover MT=128
    const int wn = (wid >> 2) * 64;    // 4 n-groups of 64 (2 tiles each)

    const int base_n = blockIdx.x * MT;
    const int bq = base_n >> 10;          // batch (SS = 1024)
    const int sb = base_n & (SS - 1);     // spatial base

    // B staging assignment (1024 threads)
    const int cod_b = tid & 255;          // one code
    const int pB = (tid >> 8) & 1;        // 0=h, 1=l
    const int oB = tid >> 9;              // 0..1: quad-pair within chunk

    // A bases
    //  PRE: packed plane, d-pair row dp = dt/2 + t*8 + half*4 + j, col sb+wm+colk
    const uint* axh = reinterpret_cast<const uint*>(out)
                      + (size_t)bq * XSLAB + (size_t)(half * 4) * SS
                      + sb + wm + colk;
    //  !PRE: f32, d = dt + t*16 + half*8 + j
    const float* xw = x + ((size_t)bq * DD + half * 8) * SS + sb + wm + colk;

    floatx16 acc[2];                      // 2 n-tiles (wn, wn+32)
#pragma unroll
    for (int j = 0; j < 2; ++j) acc[j] = (floatx16)(0.0f);

    float bestv[16];
    int bestc[16];
#pragma unroll
    for (int r = 0; r < 16; ++r) { bestv[r] = 3.4e38f; bestc[r] = 0; }

    // B register sets (distance-2 prefetch, static naming)
    uint4 u00, u01, u10, u11;
    float fb0[16], fb1[16];
    // A registers (single set per step)
    uint uah[8], ual[8];   // PRE: pair-words, [t*4+j]
    float fa[16];          // !PRE raw f32

    // ---- helpers ----
    auto issueA = [&](int c) {
        if constexpr (PRE) {
            const int dp0 = (c & 7) * (CD / 2);
#pragma unroll
            for (int t = 0; t < 2; ++t)
#pragma unroll
                for (int j = 0; j < 4; ++j) {
                    uah[t * 4 + j] = axh[(size_t)(dp0 + t * 8 + j) * SS];
                    ual[t * 4 + j] = axh[(size_t)(dp0 + t * 8 + j) * SS + XPLANE];
                }
        } else {
            const int dt = (c & 7) * CD;
#pragma unroll
            for (int t = 0; t < 2; ++t)
#pragma unroll
                for (int j = 0; j < 8; ++j)
                    fa[t * 8 + j] = xw[(size_t)(dt + t * 16 + j) * SS];
        }
    };
    auto issueB = [&](int c, uint4& a0, uint4& a1, float (&fb)[16]) {
        const int kt = c >> 3;
        const int dt = (c & 7) * CD;
        if constexpr (PRE) {
            const int qg = (dt >> 3) + 2 * oB;
            const size_t kb = (size_t)kt * NTT + cod_b;
            a0 = epk[(size_t)(qg * 2 + pB) * KK + kb];
            a1 = epk[(size_t)((qg + 1) * 2 + pB) * KK + kb];
        } else {
#pragma unroll
            for (int i = 0; i < 16; ++i)
                fb[i] = emb[(size_t)(dt + oB * 16 + i) * KK
                            + (size_t)kt * NTT + cod_b];
        }
    };
    auto stageWrite = [&](int nxt, uint4& a0, uint4& a1, float (&fb)[16]) {
        uint4 w0, w1;
        if constexpr (PRE) {
            w0 = a0; w1 = a1;
        } else {
            ushort hh[16], ll[16];
#pragma unroll
            for (int i = 0; i < 16; ++i) split16(fb[i], hh[i], ll[i]);
            const ushort* s = pB ? ll : hh;
            w0.x = pk(s[0], s[1]);   w0.y = pk(s[2], s[3]);
            w0.z = pk(s[4], s[5]);   w0.w = pk(s[6], s[7]);
            w1.x = pk(s[8], s[9]);   w1.y = pk(s[10], s[11]);
            w1.z = pk(s[12], s[13]); w1.w = pk(s[14], s[15]);
        }
        ushort* Bp = pB ? &Bl[nxt][0] : &Bh[nxt][0];
        *reinterpret_cast<uint4*>(&Bp[cod_b * LDA + oB * 16]) = w0;
        *reinterpret_cast<uint4*>(&Bp[cod_b * LDA + oB * 16 + 8]) = w1;
    };
    auto compute = [&](int cur) {
        const int fo = colk * LDA + half * 8;
#pragma unroll
        for (int t = 0; t < 2; ++t) {
            FragU ah, al;
            if constexpr (PRE) {
#pragma unroll
                for (int j = 0; j < 4; ++j) {
                    ah.u[j] = uah[t * 4 + j];
                    al.u[j] = ual[t * 4 + j];
                }
            } else {
                ushort h[8], l[8];
#pragma unroll
                for (int j = 0; j < 8; ++j) split16(fa[t * 8 + j], h[j], l[j]);
#pragma unroll
                for (int j = 0; j < 4; ++j) {
                    ah.u[j] = pk(h[2 * j], h[2 * j + 1]);
                    al.u[j] = pk(l[2 * j], l[2 * j + 1]);
                }
            }
            const int o = t * 16;
            half8v bh0 = *reinterpret_cast<const half8v*>(&Bh[cur][fo + wn * LDA + o]);
            half8v bh1 = *reinterpret_cast<const half8v*>(&Bh[cur][fo + (wn + 32) * LDA + o]);
            half8v bl0 = *reinterpret_cast<const half8v*>(&Bl[cur][fo + wn * LDA + o]);
            half8v bl1 = *reinterpret_cast<const half8v*>(&Bl[cur][fo + (wn + 32) * LDA + o]);

            acc[0] = MFMA_F16(ah.v, bh0, acc[0], 0, 0, 0);
            acc[0] = MFMA_F16(ah.v, bl0, acc[0], 0, 0, 0);
            acc[0] = MFMA_F16(al.v, bh0, acc[0], 0, 0, 0);

            acc[1] = MFMA_F16(ah.v, bh1, acc[1], 0, 0, 0);
            acc[1] = MFMA_F16(ah.v, bl1, acc[1], 0, 0, 0);
            acc[1] = MFMA_F16(al.v, bh1, acc[1], 0, 0, 0);
        }
    };
    auto epilogue = [&](int kt) {
        const int cd0 = kt * NTT + wn + colk;
        const int cd1 = cd0 + 32;
        const float h0 = hn[cd0];
        const float h1 = hn[cd1];
#pragma unroll
        for (int r = 0; r < 16; ++r) {
            float s0 = h0 - acc[0][r];
            float s1 = h1 - acc[1][r];
            float v = s0; int cd = cd0;
            if (s1 < s0) { v = s1; cd = cd1; }   // strict <: smaller code wins ties
            if (v < bestv[r]) { bestv[r] = v; bestc[r] = cd; }
            acc[0][r] = 0.f;
            acc[1][r] = 0.f;
        }
    };

    // ---- prologue: stage B chunk 0, issue B chunk 1 ----
    issueB(0, u00, u01, fb0);
    stageWrite(0, u00, u01, fb0);                // one exposed vmcnt wait
    issueB(1, u10, u11, fb1);                    // in flight across barrier
    __syncthreads();

    // ---- main loop: 64 chunks (8 kt x 8 dt of K-depth 32), 2 per iter ----
    for (int cc = 0; cc < 32; ++cc) {
        const int c0 = cc * 2;
        // even step: compute buf0/chunk c0; write buf1 with c0+1
        if (c0 + 2 < 64) { issueB(c0 + 2, u00, u01, fb0); }
        issueA(c0);                              // L2/L3 hits, hidden by stage
        stageWrite(1, u10, u11, fb1);            // data(c0+1): issued 1 chunk ago
        compute(0);
        __syncthreads();

        // odd step: compute buf1/chunk c1; write buf0 with c1+1
        const int c1 = c0 + 1;
        if (c1 + 2 < 64) { issueB(c1 + 2, u10, u11, fb1); }
        issueA(c1);
        if (c1 + 1 < 64) { stageWrite(0, u00, u01, fb0); }
        compute(1);
        if ((c1 & 7) == 7) epilogue(c1 >> 3);
        __syncthreads();
    }

    // ---- cross-lane argmin: butterfly over the 32 colk lanes ----
#pragma unroll
    for (int r = 0; r < 16; ++r) {
        float v = bestv[r];
        int cd = bestc[r];
#pragma unroll
        for (int mk = 1; mk < 32; mk <<= 1) {
            float ov = __shfl_xor(v, mk);
            int oc = __shfl_xor(cd, mk);
            if (ov < v || (ov == v && oc < cd)) { v = ov; cd = oc; }
        }
        if (colk == 0) {
            const int row = (r & 3) + 8 * (r >> 2) + 4 * half;  // verified C/D map
            sv[wid >> 2][wm + row] = v;
            sc[wid >> 2][wm + row] = cd;
        }
    }
    __syncthreads();
    // ---- combine the 4 n-wave groups ----
    if (tid < MT) {
        float v = sv[0][tid]; int cd = sc[0][tid];
#pragma unroll
        for (int g = 1; g < 4; ++g) {
            float ov = sv[g][tid]; int oc = sc[g][tid];
            if (ov < v || (ov == v && oc < cd)) { v = ov; cd = oc; }
        }
        bc[tid] = cd;
    }
    __syncthreads();
    // ---- fused gather: out[(bq*DD+d)*SS + sb + m] = emb[d*KK + bc[m]] ----
    {
        const int mq = tid & 31;     // float4 group along m (128 cols = 32 groups)
        const int dg = tid >> 5;     // 0..31, 8 d's each
        const int k0 = bc[mq * 4 + 0];
        const int k1 = bc[mq * 4 + 1];
        const int k2 = bc[mq * 4 + 2];
        const int k3 = bc[mq * 4 + 3];
#pragma unroll 4
        for (int dd = 0; dd < 8; ++dd) {
            const int d = dg * 8 + dd;
            const float* er = emb + (size_t)d * KK;
            float4 o = make_float4(er[k0], er[k1], er[k2], er[k3]);
            reinterpret_cast<float4*>(&out[((size_t)bq * DD + d) * SS + sb])[mq] = o;
        }
    }
}

extern "C" void kernel_launch(void* const* d_in, const int* in_sizes, int n_in,
                              void* d_out, int out_size, void* d_ws, size_t ws_size,
                              hipStream_t stream) {
    const float* x = (const float*)d_in[0];     // (32,256,32,32)
    const float* emb = (const float*)d_in[1];   // (256,2048)
    float* out = (float*)d_out;
    float* hn = (float*)d_ws;                   // 2048 f32 = 8 KB (proven safe)
    uint4* epk = (uint4*)((char*)d_ws + KK * sizeof(float));  // 2 MB packed emb

    // 32 quads * 2 planes * 2048 codes * 16 B = 2 MB
    const size_t need = (size_t)KK * 4 + (size_t)32 * 2 * KK * 16;

    hipLaunchKernelGGL(hn_kernel, dim3(KK / 32), dim3(256), 0, stream, emb, hn);
    if (ws_size >= need) {
        hipLaunchKernelGGL(pack_emb, dim3(65536 / 256), dim3(256), 0, stream,
                           emb, epk);
        hipLaunchKernelGGL(pack_x, dim3(4096), dim3(256), 0, stream,
                           x, (uint*)out);
        hipLaunchKernelGGL((vq_fused<true>), dim3(NN / MT), dim3(1024), 0, stream,
                           x, emb, hn, epk, out);
    } else {
        hipLaunchKernelGGL((vq_fused<false>), dim3(NN / MT), dim3(1024), 0, stream,
                           x, emb, hn, epk, out);
    }
}

// Round 10
// 211.841 us; speedup vs baseline: 1.1965x; 1.1965x over previous
//
#include <hip/hip_runtime.h>

// VQ nearest-embedding, fused split-fp16 MFMA, double-buffered LDS.
// argmin_k ||x-e_k||^2 == argmin_k (0.5*||e_k||^2 - x.e_k).
// x = xh+xl, e = eh+el (fp16 RNE splits); 3 MFMA terms (hh, hl, lh).
// R12 (143us, best): 1024 thr, 16 waves 4m x 4n, CD=32, LDA=40, quad epk,
//      distance-2 prefetch. 6.3M conflicts = A b32 staging writes
//      (8-way: 64 consecutive rows x fixed slot, bank cosets mod 4).
// R13 (163us): A split in-loop -> VALU x4 dup. R14 (184us): A packed in
//      out-scratch -> HBM write storm. Both A-out-of-LDS paths dead.
// R15: R12 + STAGING THREAD REMAP ONLY. Each wave now covers
//      8 rows x 8 d2a slots (lat_a = (tid&7)+8*(tid>>6), d2a=(tid>>3)&7)
//      instead of 64 rows x 1 slot. Write banks (20r+q), r,q in 0..7:
//      every bank hit exactly 2x -> free. Same bytes, same slots, same
//      split work -> LDS bit-identical -> absmax 0. A global loads become
//      8x32B clusters (L2-resident x, negligible). B path untouched.

typedef __attribute__((ext_vector_type(8))) _Float16 half8v;  // 8 fp16 = 4 VGPRs
typedef __attribute__((ext_vector_type(16))) float floatx16;  // 32x32 acc
typedef unsigned int uint;
typedef unsigned short ushort;

#define DD 256
#define KK 2048
#define SS 1024
#define NN 32768
#define MT 128      // latents per block
#define NTT 256     // codes per kt tile (8 tiles cover K=2048)
#define CD 32       // chunk K-depth (halfs)
#define LDA 40      // LDS row stride in fp16 elems (80 B: 16B-aligned)
#define MFMA_F16 __builtin_amdgcn_mfma_f32_32x32x16_f16

union HU { _Float16 f; ushort u; };

__device__ __forceinline__ void split16(float v, ushort& h, ushort& l) {
    HU a, b;
    a.f = (_Float16)v;                       // RNE
    b.f = (_Float16)(v - (float)a.f);
    h = a.u; l = b.u;
}

__device__ __forceinline__ uint pk(ushort a, ushort b) {
    return (uint)a | ((uint)b << 16);
}

// 64 blocks: block b covers codes [b*32, b*32+32); 8 threads/code sum 32 d's.
__global__ __launch_bounds__(256) void hn_kernel(const float* __restrict__ emb,
                                                 float* __restrict__ hn) {
    __shared__ float red[256];
    const int tid = threadIdx.x;
    const int k = blockIdx.x * 32 + (tid & 31);
    const int j = tid >> 5;              // 0..7: d-chunk
    float a = 0.f;
#pragma unroll
    for (int i = 0; i < 32; ++i) {
        float e = emb[(size_t)(j * 32 + i) * KK + k];
        a += e * e;
    }
    red[tid] = a;
    __syncthreads();
    if (j == 0) {
        float s = a;
#pragma unroll
        for (int g = 1; g < 8; ++g) s += red[g * 32 + (tid & 31)];
        hn[k] = 0.5f * s;
    }
}

// emb (d,k) f32 -> epk quad-interleaved uint4 planes:
//   uint4 index (q*2 + p)*KK + k   holds, for plane p in {h,l}, code k,
//   packed d-pairs of quad q (element j = pack(d=8q+2j, d=8q+2j+1)).
__global__ __launch_bounds__(256) void pack_emb(const float* __restrict__ emb,
                                                uint4* __restrict__ epk) {
    int idx = blockIdx.x * 256 + threadIdx.x;     // 65536 = 32 quads * 2048 k
    int k = idx & (KK - 1);
    int q = idx >> 11;                            // d-quad: d = 8q..8q+7
    ushort h[8], l[8];
#pragma unroll
    for (int j = 0; j < 8; ++j) {
        float e = emb[(size_t)(8 * q + j) * KK + k];
        split16(e, h[j], l[j]);
    }
    uint4 H, L;
    H.x = pk(h[0], h[1]); H.y = pk(h[2], h[3]);
    H.z = pk(h[4], h[5]); H.w = pk(h[6], h[7]);
    L.x = pk(l[0], l[1]); L.y = pk(l[2], l[3]);
    L.z = pk(l[4], l[5]); L.w = pk(l[6], l[7]);
    epk[(size_t)(q * 2 + 0) * KK + k] = H;
    epk[(size_t)(q * 2 + 1) * KK + k] = L;
}

// PRE: B from quad-packed epk (dwordx4). !PRE: B from emb f32 + in-loop split.
template <bool PRE>
__global__ __launch_bounds__(1024, 4) void vq_fused(
        const float* __restrict__ x, const float* __restrict__ emb,
        const float* __restrict__ hn, const uint4* __restrict__ epk,
        float* __restrict__ out) {
    __shared__ ushort Ah[2][MT * LDA], Al[2][MT * LDA];     // 10 KB each plane/buf
    __shared__ ushort Bh[2][NTT * LDA], Bl[2][NTT * LDA];   // 20 KB each plane/buf
    __shared__ float sv[4][MT];
    __shared__ int   sc[4][MT];
    __shared__ int   bc[MT];

    const int tid = threadIdx.x;
    const int lane = tid & 63;
    const int wid = tid >> 6;          // 16 waves: 4(m) x 4(n)
    const int colk = lane & 31;
    const int half = lane >> 5;
    const int wm = (wid & 3) * 32;     // 4 m-tiles of 32 cover MT=128
    const int wn = (wid >> 2) * 64;    // 4 n-groups of 64 (2 tiles each)

    const int base_n = blockIdx.x * MT;
    const int bq = base_n >> 10;          // batch (SS = 1024)
    const int sb = base_n & (SS - 1);     // spatial base

    // staging assignment (1024 threads)
    // R15 REMAP: wave covers 8 rows x 8 slots -> A writes 2-way (free).
    const int lat_a = (tid & 7) + 8 * (tid >> 6);   // latent row
    const int d2a = (tid >> 3) & 7;                 // d-pair slot (varies in-wave)
    const int cod_b = tid & 255;          // B: one code
    const int pB = (tid >> 8) & 1;        // 0=h, 1=l
    const int oB = tid >> 9;              // 0..1: quad-pair within chunk

    const float* xA = x + ((size_t)bq * DD + 2 * d2a) * SS + sb + lat_a;

    floatx16 acc[2];                      // 2 n-tiles (wn, wn+32)
#pragma unroll
    for (int j = 0; j < 2; ++j) acc[j] = (floatx16)(0.0f);

    float bestv[16];
    int bestc[16];
#pragma unroll
    for (int r = 0; r < 16; ++r) { bestv[r] = 3.4e38f; bestc[r] = 0; }

    // two named register sets (static indexing — no dynamic array idx)
    float fa0[4], fa1[4];
    uint4 u00, u01, u10, u11;
    float fb0[16], fb1[16];

    // ---- helpers ----
    auto issueA = [&](int c, float (&fa)[4]) {
        const int dt = (c & 7) * CD;
        fa[0] = xA[(size_t)(dt + 0) * SS];
        fa[1] = xA[(size_t)(dt + 1) * SS];
        fa[2] = xA[(size_t)(dt + 16) * SS];
        fa[3] = xA[(size_t)(dt + 17) * SS];
    };
    auto issueB = [&](int c, uint4& a0, uint4& a1, float (&fb)[16]) {
        const int kt = c >> 3;
        const int dt = (c & 7) * CD;
        if constexpr (PRE) {
            const int qg = (dt >> 3) + 2 * oB;
            const size_t kb = (size_t)kt * NTT + cod_b;
            a0 = epk[(size_t)(qg * 2 + pB) * KK + kb];
            a1 = epk[(size_t)((qg + 1) * 2 + pB) * KK + kb];
        } else {
#pragma unroll
            for (int i = 0; i < 16; ++i)
                fb[i] = emb[(size_t)(dt + oB * 16 + i) * KK
                            + (size_t)kt * NTT + cod_b];
        }
    };
    auto stageWrite = [&](int nxt, float (&fa)[4], uint4& a0, uint4& a1,
                          float (&fb)[16]) {
        ushort h0, l0, h1, l1, h2, l2, h3, l3;
        split16(fa[0], h0, l0); split16(fa[1], h1, l1);
        split16(fa[2], h2, l2); split16(fa[3], h3, l3);
        *reinterpret_cast<uint*>(&Ah[nxt][lat_a * LDA + 2 * d2a]) = pk(h0, h1);
        *reinterpret_cast<uint*>(&Al[nxt][lat_a * LDA + 2 * d2a]) = pk(l0, l1);
        *reinterpret_cast<uint*>(&Ah[nxt][lat_a * LDA + 2 * d2a + 16]) = pk(h2, h3);
        *reinterpret_cast<uint*>(&Al[nxt][lat_a * LDA + 2 * d2a + 16]) = pk(l2, l3);
        uint4 w0, w1;
        if constexpr (PRE) {
            w0 = a0; w1 = a1;
        } else {
            ushort hh[16], ll[16];
#pragma unroll
            for (int i = 0; i < 16; ++i) split16(fb[i], hh[i], ll[i]);
            const ushort* s = pB ? ll : hh;
            w0.x = pk(s[0], s[1]);   w0.y = pk(s[2], s[3]);
            w0.z = pk(s[4], s[5]);   w0.w = pk(s[6], s[7]);
            w1.x = pk(s[8], s[9]);   w1.y = pk(s[10], s[11]);
            w1.z = pk(s[12], s[13]); w1.w = pk(s[14], s[15]);
        }
        ushort* Bp = pB ? &Bl[nxt][0] : &Bh[nxt][0];
        *reinterpret_cast<uint4*>(&Bp[cod_b * LDA + oB * 16]) = w0;
        *reinterpret_cast<uint4*>(&Bp[cod_b * LDA + oB * 16 + 8]) = w1;
    };
    auto compute = [&](int cur) {
        const int fo = colk * LDA + half * 8;
#pragma unroll
        for (int t = 0; t < 2; ++t) {
            const int o = t * 16;
            half8v ah = *reinterpret_cast<const half8v*>(&Ah[cur][fo + wm * LDA + o]);
            half8v al = *reinterpret_cast<const half8v*>(&Al[cur][fo + wm * LDA + o]);
            half8v bh0 = *reinterpret_cast<const half8v*>(&Bh[cur][fo + wn * LDA + o]);
            half8v bh1 = *reinterpret_cast<const half8v*>(&Bh[cur][fo + (wn + 32) * LDA + o]);
            half8v bl0 = *reinterpret_cast<const half8v*>(&Bl[cur][fo + wn * LDA + o]);
            half8v bl1 = *reinterpret_cast<const half8v*>(&Bl[cur][fo + (wn + 32) * LDA + o]);

            acc[0] = MFMA_F16(ah, bh0, acc[0], 0, 0, 0);
            acc[0] = MFMA_F16(ah, bl0, acc[0], 0, 0, 0);
            acc[0] = MFMA_F16(al, bh0, acc[0], 0, 0, 0);

            acc[1] = MFMA_F16(ah, bh1, acc[1], 0, 0, 0);
            acc[1] = MFMA_F16(ah, bl1, acc[1], 0, 0, 0);
            acc[1] = MFMA_F16(al, bh1, acc[1], 0, 0, 0);
        }
    };
    auto epilogue = [&](int kt) {
        const int cd0 = kt * NTT + wn + colk;
        const int cd1 = cd0 + 32;
        const float h0 = hn[cd0];
        const float h1 = hn[cd1];
#pragma unroll
        for (int r = 0; r < 16; ++r) {
            float s0 = h0 - acc[0][r];
            float s1 = h1 - acc[1][r];
            float v = s0; int cd = cd0;
            if (s1 < s0) { v = s1; cd = cd1; }   // strict <: smaller code wins ties
            if (v < bestv[r]) { bestv[r] = v; bestc[r] = cd; }
            acc[0][r] = 0.f;
            acc[1][r] = 0.f;
        }
    };

    // ---- prologue: stage chunk 0, issue chunk 1 ----
    issueA(0, fa0); issueB(0, u00, u01, fb0);
    stageWrite(0, fa0, u00, u01, fb0);           // one exposed vmcnt wait
    issueA(1, fa1); issueB(1, u10, u11, fb1);    // stays in flight over barrier
    __syncthreads();

    // ---- main loop: 64 chunks (8 kt x 8 dt of K-depth 32), 2 per iter ----
    for (int cc = 0; cc < 32; ++cc) {
        const int c0 = cc * 2;
        // even step: cur=0, nxt=1; set0 free (data c0 already in LDS)
        if (c0 + 2 < 64) { issueA(c0 + 2, fa0); issueB(c0 + 2, u00, u01, fb0); }
        stageWrite(1, fa1, u10, u11, fb1);       // data(c0+1): issued 1 chunk ago
        compute(0);
        __syncthreads();

        // odd step: cur=1, nxt=0; set1 free
        const int c1 = c0 + 1;
        if (c1 + 2 < 64) { issueA(c1 + 2, fa1); issueB(c1 + 2, u10, u11, fb1); }
        if (c1 + 1 < 64) { stageWrite(0, fa0, u00, u01, fb0); }
        compute(1);
        if ((c1 & 7) == 7) epilogue(c1 >> 3);
        __syncthreads();
    }

    // ---- cross-lane argmin: butterfly over the 32 colk lanes ----
#pragma unroll
    for (int r = 0; r < 16; ++r) {
        float v = bestv[r];
        int cd = bestc[r];
#pragma unroll
        for (int mk = 1; mk < 32; mk <<= 1) {
            float ov = __shfl_xor(v, mk);
            int oc = __shfl_xor(cd, mk);
            if (ov < v || (ov == v && oc < cd)) { v = ov; cd = oc; }
        }
        if (colk == 0) {
            const int row = (r & 3) + 8 * (r >> 2) + 4 * half;  // verified C/D map
            sv[wid >> 2][wm + row] = v;
            sc[wid >> 2][wm + row] = cd;
        }
    }
    __syncthreads();
    // ---- combine the 4 n-wave groups ----
    if (tid < MT) {
        float v = sv[0][tid]; int cd = sc[0][tid];
#pragma unroll
        for (int g = 1; g < 4; ++g) {
            float ov = sv[g][tid]; int oc = sc[g][tid];
            if (ov < v || (ov == v && oc < cd)) { v = ov; cd = oc; }
        }
        bc[tid] = cd;
    }
    __syncthreads();
    // ---- fused gather: out[(bq*DD+d)*SS + sb + m] = emb[d*KK + bc[m]] ----
    {
        const int mq = tid & 31;     // float4 group along m (128 cols = 32 groups)
        const int dg = tid >> 5;     // 0..31, 8 d's each
        const int k0 = bc[mq * 4 + 0];
        const int k1 = bc[mq * 4 + 1];
        const int k2 = bc[mq * 4 + 2];
        const int k3 = bc[mq * 4 + 3];
#pragma unroll 4
        for (int dd = 0; dd < 8; ++dd) {
            const int d = dg * 8 + dd;
            const float* er = emb + (size_t)d * KK;
            float4 o = make_float4(er[k0], er[k1], er[k2], er[k3]);
            reinterpret_cast<float4*>(&out[((size_t)bq * DD + d) * SS + sb])[mq] = o;
        }
    }
}

extern "C" void kernel_launch(void* const* d_in, const int* in_sizes, int n_in,
                              void* d_out, int out_size, void* d_ws, size_t ws_size,
                              hipStream_t stream) {
    const float* x = (const float*)d_in[0];     // (32,256,32,32)
    const float* emb = (const float*)d_in[1];   // (256,2048)
    float* out = (float*)d_out;
    float* hn = (float*)d_ws;                   // 2048 f32 = 8 KB (proven safe)
    uint4* epk = (uint4*)((char*)d_ws + KK * sizeof(float));  // 2 MB packed emb

    // 32 quads * 2 planes * 2048 codes * 16 B = 2 MB
    const size_t need = (size_t)KK * 4 + (size_t)32 * 2 * KK * 16;

    hipLaunchKernelGGL(hn_kernel, dim3(KK / 32), dim3(256), 0, stream, emb, hn);
    if (ws_size >= need) {
        hipLaunchKernelGGL(pack_emb, dim3(65536 / 256), dim3(256), 0, stream,
                           emb, epk);
        hipLaunchKernelGGL((vq_fused<true>), dim3(NN / MT), dim3(1024), 0, stream,
                           x, emb, hn, epk, out);
    } else {
        hipLaunchKernelGGL((vq_fused<false>), dim3(NN / MT), dim3(1024), 0, stream,
                           x, emb, hn, epk, out);
    }
}

// Round 11
// 210.288 us; speedup vs baseline: 1.2054x; 1.0074x over previous
//
#include <hip/hip_runtime.h>

// VQ nearest-embedding, fused split-fp16 MFMA, double-buffered LDS.
// argmin_k ||x-e_k||^2 == argmin_k (0.5*||e_k||^2 - x.e_k).
// x = xh+xl, e = eh+el (fp16 RNE splits); 3 MFMA terms (hh, hl, lh).
// R12 (143us): distance-2 prefetch. R15 (138us): staging thread remap,
//      bank conflicts 6.3M -> 0 but only -5us => NO pipe is binding
//      (LDS 59%, VALU 28%, MFMA 7%, HBM 8%). ~2000 cyc/chunk unexplained.
// R16: the explanation: __syncthreads lowers to
//      s_waitcnt vmcnt(0) lgkmcnt(0); s_barrier  -- draining our PRIVATE
//      VGPR prefetch loads at every chunk barrier. The distance-2 pipeline
//      never survived a barrier; every chunk paid load latency x16 waves.
//      Fix (T4-lite): raw barrier in the hot loop:
//        s_waitcnt lgkmcnt(0)   (LDS handoff: all ds_read/ds_write done)
//        s_barrier              (no vmcnt drain -- loads stay in flight)
//      Compiler still emits counted vmcnt(N) before stageWrite's first
//      register use (auto T4). Everything else byte-identical to R15
//      -> absmax 0.

typedef __attribute__((ext_vector_type(8))) _Float16 half8v;  // 8 fp16 = 4 VGPRs
typedef __attribute__((ext_vector_type(16))) float floatx16;  // 32x32 acc
typedef unsigned int uint;
typedef unsigned short ushort;

#define DD 256
#define KK 2048
#define SS 1024
#define NN 32768
#define MT 128      // latents per block
#define NTT 256     // codes per kt tile (8 tiles cover K=2048)
#define CD 32       // chunk K-depth (halfs)
#define LDA 40      // LDS row stride in fp16 elems (80 B: 16B-aligned)
#define MFMA_F16 __builtin_amdgcn_mfma_f32_32x32x16_f16

union HU { _Float16 f; ushort u; };

__device__ __forceinline__ void split16(float v, ushort& h, ushort& l) {
    HU a, b;
    a.f = (_Float16)v;                       // RNE
    b.f = (_Float16)(v - (float)a.f);
    h = a.u; l = b.u;
}

__device__ __forceinline__ uint pk(ushort a, ushort b) {
    return (uint)a | ((uint)b << 16);
}

// Raw barrier: drain LDS ops only; leave global loads (private VGPR
// destinations) in flight across the barrier.
__device__ __forceinline__ void barrier_nodrain() {
    asm volatile("s_waitcnt lgkmcnt(0)" ::: "memory");
    __builtin_amdgcn_s_barrier();
}

// 64 blocks: block b covers codes [b*32, b*32+32); 8 threads/code sum 32 d's.
__global__ __launch_bounds__(256) void hn_kernel(const float* __restrict__ emb,
                                                 float* __restrict__ hn) {
    __shared__ float red[256];
    const int tid = threadIdx.x;
    const int k = blockIdx.x * 32 + (tid & 31);
    const int j = tid >> 5;              // 0..7: d-chunk
    float a = 0.f;
#pragma unroll
    for (int i = 0; i < 32; ++i) {
        float e = emb[(size_t)(j * 32 + i) * KK + k];
        a += e * e;
    }
    red[tid] = a;
    __syncthreads();
    if (j == 0) {
        float s = a;
#pragma unroll
        for (int g = 1; g < 8; ++g) s += red[g * 32 + (tid & 31)];
        hn[k] = 0.5f * s;
    }
}

// emb (d,k) f32 -> epk quad-interleaved uint4 planes:
//   uint4 index (q*2 + p)*KK + k   holds, for plane p in {h,l}, code k,
//   packed d-pairs of quad q (element j = pack(d=8q+2j, d=8q+2j+1)).
__global__ __launch_bounds__(256) void pack_emb(const float* __restrict__ emb,
                                                uint4* __restrict__ epk) {
    int idx = blockIdx.x * 256 + threadIdx.x;     // 65536 = 32 quads * 2048 k
    int k = idx & (KK - 1);
    int q = idx >> 11;                            // d-quad: d = 8q..8q+7
    ushort h[8], l[8];
#pragma unroll
    for (int j = 0; j < 8; ++j) {
        float e = emb[(size_t)(8 * q + j) * KK + k];
        split16(e, h[j], l[j]);
    }
    uint4 H, L;
    H.x = pk(h[0], h[1]); H.y = pk(h[2], h[3]);
    H.z = pk(h[4], h[5]); H.w = pk(h[6], h[7]);
    L.x = pk(l[0], l[1]); L.y = pk(l[2], l[3]);
    L.z = pk(l[4], l[5]); L.w = pk(l[6], l[7]);
    epk[(size_t)(q * 2 + 0) * KK + k] = H;
    epk[(size_t)(q * 2 + 1) * KK + k] = L;
}

// PRE: B from quad-packed epk (dwordx4). !PRE: B from emb f32 + in-loop split.
template <bool PRE>
__global__ __launch_bounds__(1024, 4) void vq_fused(
        const float* __restrict__ x, const float* __restrict__ emb,
        const float* __restrict__ hn, const uint4* __restrict__ epk,
        float* __restrict__ out) {
    __shared__ ushort Ah[2][MT * LDA], Al[2][MT * LDA];     // 10 KB each plane/buf
    __shared__ ushort Bh[2][NTT * LDA], Bl[2][NTT * LDA];   // 20 KB each plane/buf
    __shared__ float sv[4][MT];
    __shared__ int   sc[4][MT];
    __shared__ int   bc[MT];

    const int tid = threadIdx.x;
    const int lane = tid & 63;
    const int wid = tid >> 6;          // 16 waves: 4(m) x 4(n)
    const int colk = lane & 31;
    const int half = lane >> 5;
    const int wm = (wid & 3) * 32;     // 4 m-tiles of 32 cover MT=128
    const int wn = (wid >> 2) * 64;    // 4 n-groups of 64 (2 tiles each)

    const int base_n = blockIdx.x * MT;
    const int bq = base_n >> 10;          // batch (SS = 1024)
    const int sb = base_n & (SS - 1);     // spatial base

    // staging assignment (1024 threads)
    // R15 remap: wave covers 8 rows x 8 slots -> A writes 2-way (free).
    const int lat_a = (tid & 7) + 8 * (tid >> 6);   // latent row
    const int d2a = (tid >> 3) & 7;                 // d-pair slot (varies in-wave)
    const int cod_b = tid & 255;          // B: one code
    const int pB = (tid >> 8) & 1;        // 0=h, 1=l
    const int oB = tid >> 9;              // 0..1: quad-pair within chunk

    const float* xA = x + ((size_t)bq * DD + 2 * d2a) * SS + sb + lat_a;

    floatx16 acc[2];                      // 2 n-tiles (wn, wn+32)
#pragma unroll
    for (int j = 0; j < 2; ++j) acc[j] = (floatx16)(0.0f);

    float bestv[16];
    int bestc[16];
#pragma unroll
    for (int r = 0; r < 16; ++r) { bestv[r] = 3.4e38f; bestc[r] = 0; }

    // two named register sets (static indexing — no dynamic array idx)
    float fa0[4], fa1[4];
    uint4 u00, u01, u10, u11;
    float fb0[16], fb1[16];

    // ---- helpers ----
    auto issueA = [&](int c, float (&fa)[4]) {
        const int dt = (c & 7) * CD;
        fa[0] = xA[(size_t)(dt + 0) * SS];
        fa[1] = xA[(size_t)(dt + 1) * SS];
        fa[2] = xA[(size_t)(dt + 16) * SS];
        fa[3] = xA[(size_t)(dt + 17) * SS];
    };
    auto issueB = [&](int c, uint4& a0, uint4& a1, float (&fb)[16]) {
        const int kt = c >> 3;
        const int dt = (c & 7) * CD;
        if constexpr (PRE) {
            const int qg = (dt >> 3) + 2 * oB;
            const size_t kb = (size_t)kt * NTT + cod_b;
            a0 = epk[(size_t)(qg * 2 + pB) * KK + kb];
            a1 = epk[(size_t)((qg + 1) * 2 + pB) * KK + kb];
        } else {
#pragma unroll
            for (int i = 0; i < 16; ++i)
                fb[i] = emb[(size_t)(dt + oB * 16 + i) * KK
                            + (size_t)kt * NTT + cod_b];
        }
    };
    auto stageWrite = [&](int nxt, float (&fa)[4], uint4& a0, uint4& a1,
                          float (&fb)[16]) {
        ushort h0, l0, h1, l1, h2, l2, h3, l3;
        split16(fa[0], h0, l0); split16(fa[1], h1, l1);
        split16(fa[2], h2, l2); split16(fa[3], h3, l3);
        *reinterpret_cast<uint*>(&Ah[nxt][lat_a * LDA + 2 * d2a]) = pk(h0, h1);
        *reinterpret_cast<uint*>(&Al[nxt][lat_a * LDA + 2 * d2a]) = pk(l0, l1);
        *reinterpret_cast<uint*>(&Ah[nxt][lat_a * LDA + 2 * d2a + 16]) = pk(h2, h3);
        *reinterpret_cast<uint*>(&Al[nxt][lat_a * LDA + 2 * d2a + 16]) = pk(l2, l3);
        uint4 w0, w1;
        if constexpr (PRE) {
            w0 = a0; w1 = a1;
        } else {
            ushort hh[16], ll[16];
#pragma unroll
            for (int i = 0; i < 16; ++i) split16(fb[i], hh[i], ll[i]);
            const ushort* s = pB ? ll : hh;
            w0.x = pk(s[0], s[1]);   w0.y = pk(s[2], s[3]);
            w0.z = pk(s[4], s[5]);   w0.w = pk(s[6], s[7]);
            w1.x = pk(s[8], s[9]);   w1.y = pk(s[10], s[11]);
            w1.z = pk(s[12], s[13]); w1.w = pk(s[14], s[15]);
        }
        ushort* Bp = pB ? &Bl[nxt][0] : &Bh[nxt][0];
        *reinterpret_cast<uint4*>(&Bp[cod_b * LDA + oB * 16]) = w0;
        *reinterpret_cast<uint4*>(&Bp[cod_b * LDA + oB * 16 + 8]) = w1;
    };
    auto compute = [&](int cur) {
        const int fo = colk * LDA + half * 8;
#pragma unroll
        for (int t = 0; t < 2; ++t) {
            const int o = t * 16;
            half8v ah = *reinterpret_cast<const half8v*>(&Ah[cur][fo + wm * LDA + o]);
            half8v al = *reinterpret_cast<const half8v*>(&Al[cur][fo + wm * LDA + o]);
            half8v bh0 = *reinterpret_cast<const half8v*>(&Bh[cur][fo + wn * LDA + o]);
            half8v bh1 = *reinterpret_cast<const half8v*>(&Bh[cur][fo + (wn + 32) * LDA + o]);
            half8v bl0 = *reinterpret_cast<const half8v*>(&Bl[cur][fo + wn * LDA + o]);
            half8v bl1 = *reinterpret_cast<const half8v*>(&Bl[cur][fo + (wn + 32) * LDA + o]);

            acc[0] = MFMA_F16(ah, bh0, acc[0], 0, 0, 0);
            acc[0] = MFMA_F16(ah, bl0, acc[0], 0, 0, 0);
            acc[0] = MFMA_F16(al, bh0, acc[0], 0, 0, 0);

            acc[1] = MFMA_F16(ah, bh1, acc[1], 0, 0, 0);
            acc[1] = MFMA_F16(ah, bl1, acc[1], 0, 0, 0);
            acc[1] = MFMA_F16(al, bh1, acc[1], 0, 0, 0);
        }
    };
    auto epilogue = [&](int kt) {
        const int cd0 = kt * NTT + wn + colk;
        const int cd1 = cd0 + 32;
        const float h0 = hn[cd0];
        const float h1 = hn[cd1];
#pragma unroll
        for (int r = 0; r < 16; ++r) {
            float s0 = h0 - acc[0][r];
            float s1 = h1 - acc[1][r];
            float v = s0; int cd = cd0;
            if (s1 < s0) { v = s1; cd = cd1; }   // strict <: smaller code wins ties
            if (v < bestv[r]) { bestv[r] = v; bestc[r] = cd; }
            acc[0][r] = 0.f;
            acc[1][r] = 0.f;
        }
    };

    // ---- prologue: stage chunk 0, issue chunk 1 ----
    issueA(0, fa0); issueB(0, u00, u01, fb0);
    stageWrite(0, fa0, u00, u01, fb0);           // one exposed vmcnt wait
    issueA(1, fa1); issueB(1, u10, u11, fb1);    // stays in flight over barrier
    barrier_nodrain();

    // ---- main loop: 64 chunks (8 kt x 8 dt of K-depth 32), 2 per iter ----
    for (int cc = 0; cc < 32; ++cc) {
        const int c0 = cc * 2;
        // even step: cur=0, nxt=1; set0 free (data c0 already in LDS)
        if (c0 + 2 < 64) { issueA(c0 + 2, fa0); issueB(c0 + 2, u00, u01, fb0); }
        stageWrite(1, fa1, u10, u11, fb1);       // data(c0+1): issued 1 chunk ago
        compute(0);
        barrier_nodrain();

        // odd step: cur=1, nxt=0; set1 free
        const int c1 = c0 + 1;
        if (c1 + 2 < 64) { issueA(c1 + 2, fa1); issueB(c1 + 2, u10, u11, fb1); }
        if (c1 + 1 < 64) { stageWrite(0, fa0, u00, u01, fb0); }
        compute(1);
        if ((c1 & 7) == 7) epilogue(c1 >> 3);
        barrier_nodrain();
    }

    // ---- cross-lane argmin: butterfly over the 32 colk lanes ----
#pragma unroll
    for (int r = 0; r < 16; ++r) {
        float v = bestv[r];
        int cd = bestc[r];
#pragma unroll
        for (int mk = 1; mk < 32; mk <<= 1) {
            float ov = __shfl_xor(v, mk);
            int oc = __shfl_xor(cd, mk);
            if (ov < v || (ov == v && oc < cd)) { v = ov; cd = oc; }
        }
        if (colk == 0) {
            const int row = (r & 3) + 8 * (r >> 2) + 4 * half;  // verified C/D map
            sv[wid >> 2][wm + row] = v;
            sc[wid >> 2][wm + row] = cd;
        }
    }
    __syncthreads();
    // ---- combine the 4 n-wave groups ----
    if (tid < MT) {
        float v = sv[0][tid]; int cd = sc[0][tid];
#pragma unroll
        for (int g = 1; g < 4; ++g) {
            float ov = sv[g][tid]; int oc = sc[g][tid];
            if (ov < v || (ov == v && oc < cd)) { v = ov; cd = oc; }
        }
        bc[tid] = cd;
    }
    __syncthreads();
    // ---- fused gather: out[(bq*DD+d)*SS + sb + m] = emb[d*KK + bc[m]] ----
    {
        const int mq = tid & 31;     // float4 group along m (128 cols = 32 groups)
        const int dg = tid >> 5;     // 0..31, 8 d's each
        const int k0 = bc[mq * 4 + 0];
        const int k1 = bc[mq * 4 + 1];
        const int k2 = bc[mq * 4 + 2];
        const int k3 = bc[mq * 4 + 3];
#pragma unroll 4
        for (int dd = 0; dd < 8; ++dd) {
            const int d = dg * 8 + dd;
            const float* er = emb + (size_t)d * KK;
            float4 o = make_float4(er[k0], er[k1], er[k2], er[k3]);
            reinterpret_cast<float4*>(&out[((size_t)bq * DD + d) * SS + sb])[mq] = o;
        }
    }
}

extern "C" void kernel_launch(void* const* d_in, const int* in_sizes, int n_in,
                              void* d_out, int out_size, void* d_ws, size_t ws_size,
                              hipStream_t stream) {
    const float* x = (const float*)d_in[0];     // (32,256,32,32)
    const float* emb = (const float*)d_in[1];   // (256,2048)
    float* out = (float*)d_out;
    float* hn = (float*)d_ws;                   // 2048 f32 = 8 KB (proven safe)
    uint4* epk = (uint4*)((char*)d_ws + KK * sizeof(float));  // 2 MB packed emb

    // 32 quads * 2 planes * 2048 codes * 16 B = 2 MB
    const size_t need = (size_t)KK * 4 + (size_t)32 * 2 * KK * 16;

    hipLaunchKernelGGL(hn_kernel, dim3(KK / 32), dim3(256), 0, stream, emb, hn);
    if (ws_size >= need) {
        hipLaunchKernelGGL(pack_emb, dim3(65536 / 256), dim3(256), 0, stream,
                           emb, epk);
        hipLaunchKernelGGL((vq_fused<true>), dim3(NN / MT), dim3(1024), 0, stream,
                           x, emb, hn, epk, out);
    } else {
        hipLaunchKernelGGL((vq_fused<false>), dim3(NN / MT), dim3(1024), 0, stream,
                           x, emb, hn, epk, out);
    }
}